// Round 3
// baseline (161.661 us; speedup 1.0000x reference)
//
#include <hip/hip_runtime.h>
#include <math.h>

// AdderNet fused forward v10: one image per block, 2 waves (128 thr).
// vs v9: (1) stage-2 weights are now per-lane VECTOR loads (global_load,
// vmcnt) instead of s_load (lgkmcnt). s_load + ds_read share lgkmcnt and
// SMEM returns out-of-order -> compiler emits lgkmcnt(0) full drains at
// every weight use, serializing both pipes. Stage 3 (vector weights) never
// had the problem; stage 2 now matches it. Weights repacked 9->12 words/o
// so each o is exactly 3 aligned dwordx4. (2) stage-1 weights (48 words)
// batch-hoisted into SGPRs, opp loop fully unrolled -> one drain. (3) all
// v9 prefetch reg-copy machinery reverted (TLP already hides LDS latency;
// the movs were pure VALU cost). (4) tail = wave 0 only via shfl
// butterflies: 3 barriers instead of 6, wave 1 retires early.
//
// q(v) = round((v+8)*1024) u16; |q(a)-q(w)| = 1024*|a-w| (+-1). Pad = q(0).
// Integer requant (exact, validated R6): L1 q=max(10752-((S+2)>>2),8192)
//   L2 q=max(24832-((S+4)>>3),8192)   L3 q=max(26112-((S+8)>>4),8192)
//
// d_ws (uint words, 6960 total = 27.8 KB):
//   QW1[96]@0      [o16][kh3][{(w0,w1),(w2,0)}]           (s_load, stage 1)
//   QW2[3072]@96   [m8][o32][12] (9 used, 3 pad)           (vector, stage 2)
//   QW3[3072]@3168 [m2 16][pr8][{o0:12,o1:12}]             (vector, stage 3)
//   QW4[720]@6240  [m8][o10][pk9]                          (vector, stage 4)
//
// LDS (14,656 B -> 11 blocks/CU = 22 waves/CU):
//  sA1[2304]: A1 8 ch-pair planes x 288 words, row y at yoff1(y)=19y+(y>>1)
//             stage-2 read bank = 7i+2j mod 32 -> <=2-way (free)
//             after stage 2: A3[135]@0 (stride 17)
//  sA2[1360]: A2 16 ch-pair planes x 85 words, row y at yoff2(y)=9y+(y>>1)

#if defined(__has_builtin)
#if __has_builtin(__builtin_amdgcn_sad_u16)
#define HAS_SAD 1
#endif
#endif

__device__ __forceinline__ unsigned sadu16(unsigned a, unsigned b, unsigned acc) {
#ifdef HAS_SAD
  return __builtin_amdgcn_sad_u16(a, b, acc);
#else
  int al = (int)(a & 0xFFFFu), ah = (int)(a >> 16);
  int bl = (int)(b & 0xFFFFu), bh = (int)(b >> 16);
  return acc + (unsigned)(al > bl ? al - bl : bl - al)
             + (unsigned)(ah > bh ? ah - bh : bh - ah);
#endif
}

__device__ __forceinline__ unsigned quant(float v) {
  return (unsigned)fmaf(v, 1024.0f, 8192.5f);  // v >= -8 by construction
}
__device__ __forceinline__ unsigned quantx(float v) {  // quant(v - 0.5)
  return (unsigned)fmaf(v, 1024.0f, 7680.5f);
}
__device__ __forceinline__ int imax(int a, int b) { return a > b ? a : b; }
__device__ __forceinline__ int yoff1(int y) { return y * 19 + (y >> 1); }
__device__ __forceinline__ int yoff2(int y) { return y * 9 + (y >> 1); }

#define QPAD 0x20002000u

// ---------------- weight prep: quantize + repack into d_ws ----------------
__global__ void adder_prep(const float* __restrict__ w1, const float* __restrict__ w2,
                           const float* __restrict__ w3, const float* __restrict__ w4,
                           unsigned* __restrict__ qw) {
  int k = blockIdx.x * 256 + threadIdx.x;
  if (k < 96) {
    int o = k / 6, r = k % 6, kh = r >> 1, h = r & 1;
    const float* p = w1 + o * 9 + kh * 3;
    qw[k] = h ? quant(p[2]) : (quant(p[0]) | (quant(p[1]) << 16));
  } else if (k < 3168) {          // QW2 [m8][o32][12], 9 used
    int k2 = k - 96, m = k2 / 384, r = k2 % 384, o = r / 12, kk = r % 12;
    unsigned v = 0u;
    if (kk < 9) {
      int s = o * 144 + 2 * m * 9 + kk;
      v = quant(w2[s]) | (quant(w2[s + 9]) << 16);
    }
    qw[k] = v;
  } else if (k < 6240) {          // QW3 [m2 16][pr8][{12,12}]
    int k3 = k - 3168, m2 = k3 / 192, r = k3 % 192, pr = r / 24, rr = r % 24;
    int oo = rr / 12, kk = rr % 12;
    unsigned v = 0u;
    if (kk < 9) {
      int s = (2 * pr + oo) * 288 + 2 * m2 * 9 + kk;
      v = quant(w3[s]) | (quant(w3[s + 9]) << 16);
    }
    qw[k] = v;
  } else if (k < 6960) {          // QW4 [m8][o10][9]
    int k4 = k - 6240, m = k4 / 90, r = k4 % 90, o = r / 9, pk = r % 9;
    int s = o * 144 + 2 * m * 9 + pk;
    qw[k] = quant(w4[s]) | (quant(w4[s + 9]) << 16);
  }
}

__global__ __launch_bounds__(128, 8) void adder_main(
    const float* __restrict__ gx,
    const unsigned* __restrict__ qw,
    float* __restrict__ gout)
{
  __shared__ __align__(16) unsigned sA1[2304];
  __shared__ __align__(16) unsigned sA2[1360];

  const int t = threadIdx.x;
  const int l = t & 63;                                   // lane in wave
  const int wu = __builtin_amdgcn_readfirstlane(t >> 6);  // wave id (SGPR)
  const int b = blockIdx.x;
  const float* img = gx + (size_t)b * 784;

  // forced-VGPR zero: makes uniform weight pointers use VECTOR loads (vmcnt)
  unsigned voff;
  asm("v_mov_b32 %0, 0" : "=v"(voff));

  // ---------------- stage 0: A1 ghost border ----------------
  for (int k = t; k < 448; k += 128) {       // 8 planes x 56 perimeter cells
    int plane = k / 56, c = k % 56;
    int y, x;
    if (c < 15)      { y = 0;      x = c; }
    else if (c < 30) { y = 14;     x = c - 15; }
    else if (c < 43) { y = c - 29; x = 0; }
    else             { y = c - 42; x = 14; }
    sA1[plane * 288 + yoff1(y) + x] = QPAD;
  }

  // ------- stage 1: L1 [16,13,13]; wave w does op-pairs w*4..w*4+3 -------
  if (l < 52) {
    const int i = l >> 2, jq = l & 3;       // output rows i, cols j=4jq+jj
    unsigned wall[48];                      // 4 op-pairs x 12 words, uniform ->
    const unsigned* wbase = qw + wu * 48;   // one batched s_load, SGPR-resident
#pragma unroll
    for (int q = 0; q < 48; ++q) wall[q] = wbase[q];
    unsigned r[3][5], mw[3][4];
#pragma unroll
    for (int kh = 0; kh < 3; ++kh) {
      const float* rp = img + (2 * i + kh) * 28 + 8 * jq;
      float4 A = *(const float4*)(rp);
      float4 B = *(const float4*)(rp + 4);
      float2 C = *(const float2*)(rp + 8);
      r[kh][0] = quantx(A.x) | (quantx(A.y) << 16);
      r[kh][1] = quantx(A.z) | (quantx(A.w) << 16);
      r[kh][2] = quantx(B.x) | (quantx(B.y) << 16);
      r[kh][3] = quantx(B.z) | (quantx(B.w) << 16);
      r[kh][4] = quantx(C.x) | (quantx(C.y) << 16);
#pragma unroll
      for (int c = 0; c < 4; ++c) mw[kh][c] = r[kh][c + 1] & 0xFFFFu;
    }
    const int dbase = yoff1(i + 1) + 4 * jq + 1;
#pragma unroll
    for (int opp = 0; opp < 4; ++opp) {     // fully unrolled, static wall idx
      const int op = wu * 4 + opp;
      unsigned a0[4], a1[4];
#pragma unroll
      for (int jj = 0; jj < 4; ++jj) { a0[jj] = 0u; a1[jj] = 0u; }
#pragma unroll
      for (int kh = 0; kh < 3; ++kh) {
        unsigned wa01 = wall[opp * 12 + kh * 2], wa2 = wall[opp * 12 + kh * 2 + 1];
        unsigned wb01 = wall[opp * 12 + 6 + kh * 2], wb2 = wall[opp * 12 + 6 + kh * 2 + 1];
#pragma unroll
        for (int jj = 0; jj < 4; ++jj) {
          a0[jj] = sadu16(r[kh][jj], wa01, a0[jj]);
          a0[jj] = sadu16(mw[kh][jj], wa2, a0[jj]);
          a1[jj] = sadu16(r[kh][jj], wb01, a1[jj]);
          a1[jj] = sadu16(mw[kh][jj], wb2, a1[jj]);
        }
      }
      unsigned* dst = sA1 + op * 288 + dbase;
#pragma unroll
      for (int jj = 0; jj < 4; ++jj) {
        if (4 * jq + jj < 13) {
          int q0 = imax(10752 - (int)((a0[jj] + 2u) >> 2), 8192);
          int q1 = imax(10752 - (int)((a1[jj] + 2u) >> 2), 8192);
          dst[jj] = (unsigned)q0 | ((unsigned)q1 << 16);
        }
      }
    }
  }
  __syncthreads();

  // A2 ghost border: off stage-1 critical path; only read after barrier 2
  for (int k = t; k < 512; k += 128) {       // 16 planes x 32 perimeter cells
    int plane = k >> 5, c = k & 31;
    int y, x;
    if (c < 9)       { y = 0; x = c; }
    else if (c < 18) { y = 8; x = c - 9; }
    else if (c < 25) { y = c - 17; x = 0; }
    else             { y = c - 24; x = 8; }
    sA2[plane * 85 + yoff2(y) + x] = QPAD;
  }

  // ------- stage 2: L2 [32,7,7]; wave w does o = w*16..w*16+15 -------
  if (l < 49) {
    const int i = l / 7, j = l % 7;
    unsigned acc[16];
#pragma unroll
    for (int o = 0; o < 16; ++o) acc[o] = 0u;
    // VGPR base -> global_load (vmcnt); lgkmcnt carries only the patch reads
    const unsigned* qw2v = qw + 96 + wu * 192 + voff;
#pragma unroll 1
    for (int m = 0; m < 8; ++m) {
      const unsigned* pb = sA1 + m * 288 + 39 * i + 2 * j;
      unsigned p00 = pb[0],  p01 = pb[1],  p02 = pb[2];    // yoff1(2i)   = 39i
      unsigned p10 = pb[19], p11 = pb[20], p12 = pb[21];   // yoff1(2i+1) = +19
      unsigned p20 = pb[39], p21 = pb[40], p22 = pb[41];   // yoff1(2i+2) = +39
      const uint4* wm4 = (const uint4*)(qw2v + m * 384);   // [o16][3 x uint4]
#pragma unroll
      for (int o = 0; o < 16; ++o) {
        uint4 wa = wm4[o * 3], wb = wm4[o * 3 + 1], wc = wm4[o * 3 + 2];
        unsigned a = acc[o];
        a = sadu16(p00, wa.x, a); a = sadu16(p01, wa.y, a); a = sadu16(p02, wa.z, a);
        a = sadu16(p10, wa.w, a); a = sadu16(p11, wb.x, a); a = sadu16(p12, wb.y, a);
        a = sadu16(p20, wb.z, a); a = sadu16(p21, wb.w, a); a = sadu16(p22, wc.x, a);
        acc[o] = a;
      }
    }
#pragma unroll
    for (int m2 = 0; m2 < 8; ++m2) {        // global ch-pair = wu*8 + m2
      int q0 = imax(24832 - (int)((acc[2 * m2] + 4u) >> 3), 8192);
      int q1 = imax(24832 - (int)((acc[2 * m2 + 1] + 4u) >> 3), 8192);
      sA2[(wu * 8 + m2) * 85 + yoff2(i + 1) + (j + 1)] = (unsigned)q0 | ((unsigned)q1 << 16);
    }
  }
  __syncthreads();

  // ------- stage 3: L3 [16,4,4]; lanes = pos16 x outpair4, uniform m2 loop,
  //         per-lane vector weight loads (already vmcnt-separated) -------
  {
    const int pos = l & 15, oq = l >> 4;
    const int i = pos >> 2, j = pos & 3;
    const int pr = wu * 4 + oq;              // global output pair 0..7
    const unsigned* qw3v = qw + 3168 + pr * 24;  // lane-varying -> vector loads
    unsigned acc0 = 0u, acc1 = 0u;
#pragma unroll 1
    for (int m2 = 0; m2 < 16; ++m2) {
      const unsigned* pb = sA2 + m2 * 85 + 19 * i + 2 * j;
      unsigned p00 = pb[0],  p01 = pb[1],  p02 = pb[2];    // yoff2(2i)   = 19i
      unsigned p10 = pb[9],  p11 = pb[10], p12 = pb[11];   // yoff2(2i+1) = +9
      unsigned p20 = pb[19], p21 = pb[20], p22 = pb[21];   // yoff2(2i+2) = +19
      const uint4* w6 = (const uint4*)(qw3v + m2 * 192);
      uint4 a0 = w6[0], a1 = w6[1], a2 = w6[2];            // o = 2pr
      uint4 b0 = w6[3], b1 = w6[4], b2 = w6[5];            // o = 2pr+1
      acc0 = sadu16(p00, a0.x, acc0); acc0 = sadu16(p01, a0.y, acc0);
      acc0 = sadu16(p02, a0.z, acc0); acc0 = sadu16(p10, a0.w, acc0);
      acc0 = sadu16(p11, a1.x, acc0); acc0 = sadu16(p12, a1.y, acc0);
      acc0 = sadu16(p20, a1.z, acc0); acc0 = sadu16(p21, a1.w, acc0);
      acc0 = sadu16(p22, a2.x, acc0);
      acc1 = sadu16(p00, b0.x, acc1); acc1 = sadu16(p01, b0.y, acc1);
      acc1 = sadu16(p02, b0.z, acc1); acc1 = sadu16(p10, b0.w, acc1);
      acc1 = sadu16(p11, b1.x, acc1); acc1 = sadu16(p12, b1.y, acc1);
      acc1 = sadu16(p20, b1.z, acc1); acc1 = sadu16(p21, b1.w, acc1);
      acc1 = sadu16(p22, b2.x, acc1);
    }
    int q0 = imax(26112 - (int)((acc0 + 8u) >> 4), 8192);
    int q1 = imax(26112 - (int)((acc1 + 8u) >> 4), 8192);
    // A3 pair words [pr8][pos16] @ sA1[0..], stride 17 (A1 planes dead)
    sA1[pr * 17 + pos] = (unsigned)q0 | ((unsigned)q1 << 16);
  }
  __syncthreads();

  // ------- stage 4 + log_softmax: wave 0 only, shfl butterflies, no barriers;
  //         wave 1 retires here -------
  if (wu == 0) {
    unsigned acc = 0u;
    const int o = t % 10, mq = t / 10;       // meaningful for t<40
    if (t < 40) {
      const unsigned* qw4 = qw + 6240;
#pragma unroll
      for (int mm = 0; mm < 2; ++mm) {
        const int m = mq * 2 + mm;
        const unsigned* a3 = sA1 + m * 17;
        const unsigned* w9 = qw4 + (m * 10 + o) * 9;  // per-lane -> vector
#pragma unroll
        for (int kh = 0; kh < 3; ++kh)
#pragma unroll
          for (int kw = 0; kw < 3; ++kw)
            acc = sadu16(a3[kh * 4 + kw], w9[kh * 3 + kw], acc);
      }
    }
    // reduce mq groups: lane t<10 needs acc from t, t+10, t+20, t+30
    unsigned s = acc + (unsigned)__shfl((int)acc, t + 10)
                     + (unsigned)__shfl((int)acc, t + 20)
                     + (unsigned)__shfl((int)acc, t + 30);
    float lg = (t < 10) ? -(float)s * (1.0f / 1024.0f) : -1e30f;
    float mx = lg;
#pragma unroll
    for (int d = 8; d >= 1; d >>= 1) mx = fmaxf(mx, __shfl_xor(mx, d));
    float e = (t < 10) ? __expf(lg - mx) : 0.0f;
    float sum = e;
#pragma unroll
    for (int d = 8; d >= 1; d >>= 1) sum += __shfl_xor(sum, d);
    if (t < 10)
      gout[(size_t)b * 10 + t] = lg - mx - __logf(sum);
  }
}

extern "C" void kernel_launch(void* const* d_in, const int* in_sizes, int n_in,
                              void* d_out, int out_size, void* d_ws, size_t ws_size,
                              hipStream_t stream) {
  const float* x  = (const float*)d_in[0];
  const float* w1 = (const float*)d_in[1];
  const float* w2 = (const float*)d_in[2];
  const float* w3 = (const float*)d_in[3];
  const float* w4 = (const float*)d_in[4];
  unsigned* qw = (unsigned*)d_ws;           // 6960 words = 27.8 KB
  float* out = (float*)d_out;
  adder_prep<<<28, 256, 0, stream>>>(w1, w2, w3, w4, qw);
  adder_main<<<4096, 128, 0, stream>>>(x, qw, out);
}

// Round 4
// 103.040 us; speedup vs baseline: 1.5689x; 1.5689x over previous
//
#include <hip/hip_runtime.h>
#include <math.h>

// AdderNet fused forward v11: one image per block, 4 waves (256 thr).
// v10's vector-weight experiment REVERTED (uniform s_load broadcast was
// never the bottleneck; vmcnt-parking halved perf). v11 attacks the real
// limiter per v8/v9 data: wave starvation (VALUBusy 56% @ 5.5 waves/SIMD).
// 4 waves/image -> 8 blocks/CU x 4 = 32 waves/CU (the HW cap), halving the
// per-wave serial path again:
//   stage1: 2 op-pairs/wave (weights SGPR-hoisted, one lgkm drain)
//   stage2: 8 output-ch accs/wave, s_load weights, odd-bank swizzle
//   stage3: all 64 lanes = pos16 x opair2 x m2half2, shfl_xor(32) reduce
//   tail:   wave 0 only, shfl butterflies; 3 barriers total
//
// q(v) = round((v+8)*1024) u16; |q(a)-q(w)| = 1024*|a-w| (+-1). Pad = q(0).
// Integer requant (exact, validated R6): L1 q=max(10752-((S+2)>>2),8192)
//   L2 q=max(24832-((S+4)>>3),8192)   L3 q=max(26112-((S+8)>>4),8192)
//
// d_ws (uint words, 5424 = 21.7 KB):
//   QW1[96]@0      [o16][kh3][{(w0,w1),(w2,0)}]   (s_load, stage 1)
//   QW2[2304]@96   [m8][o32][pk9]                  (s_load, stage 2)
//   QW3[2304]@2400 [m2 16][o16][pk9]               (per-lane vector, stage 3)
//   QW4[720]@4704  [m8][o10][pk9]                  (per-lane vector, stage 4)
//
// LDS (14,656 B; 8 blocks/CU by the 32-wave cap):
//  sA1[2304]: A1 8 ch-pair planes x 288 words, row y at yoff1(y)=19y+(y>>1)
//             stage-2 read bank = 7i+2j mod 32 -> <=2-way (free)
//             after stage 2: A3[135]@0 (stride 17)
//  sA2[1360]: A2 16 ch-pair planes x 85 words, row y at yoff2(y)=9y+(y>>1)

#if defined(__has_builtin)
#if __has_builtin(__builtin_amdgcn_sad_u16)
#define HAS_SAD 1
#endif
#endif

__device__ __forceinline__ unsigned sadu16(unsigned a, unsigned b, unsigned acc) {
#ifdef HAS_SAD
  return __builtin_amdgcn_sad_u16(a, b, acc);
#else
  int al = (int)(a & 0xFFFFu), ah = (int)(a >> 16);
  int bl = (int)(b & 0xFFFFu), bh = (int)(b >> 16);
  return acc + (unsigned)(al > bl ? al - bl : bl - al)
             + (unsigned)(ah > bh ? ah - bh : bh - ah);
#endif
}

__device__ __forceinline__ unsigned quant(float v) {
  return (unsigned)fmaf(v, 1024.0f, 8192.5f);  // v >= -8 by construction
}
__device__ __forceinline__ unsigned quantx(float v) {  // quant(v - 0.5)
  return (unsigned)fmaf(v, 1024.0f, 7680.5f);
}
__device__ __forceinline__ int imax(int a, int b) { return a > b ? a : b; }
__device__ __forceinline__ int yoff1(int y) { return y * 19 + (y >> 1); }
__device__ __forceinline__ int yoff2(int y) { return y * 9 + (y >> 1); }

#define QPAD 0x20002000u

// ---------------- weight prep: quantize + repack into d_ws ----------------
__global__ void adder_prep(const float* __restrict__ w1, const float* __restrict__ w2,
                           const float* __restrict__ w3, const float* __restrict__ w4,
                           unsigned* __restrict__ qw) {
  int k = blockIdx.x * 256 + threadIdx.x;
  if (k < 96) {
    int o = k / 6, r = k % 6, kh = r >> 1, h = r & 1;
    const float* p = w1 + o * 9 + kh * 3;
    qw[k] = h ? quant(p[2]) : (quant(p[0]) | (quant(p[1]) << 16));
  } else if (k < 2400) {
    int k2 = k - 96, m = k2 / 288, r = k2 % 288, o = r / 9, pk = r % 9;
    int s = o * 144 + 2 * m * 9 + pk;
    qw[k] = quant(w2[s]) | (quant(w2[s + 9]) << 16);
  } else if (k < 4704) {
    int k3 = k - 2400, m2 = k3 / 144, r = k3 % 144, o = r / 9, pk = r % 9;
    int s = o * 288 + 2 * m2 * 9 + pk;
    qw[k] = quant(w3[s]) | (quant(w3[s + 9]) << 16);
  } else if (k < 5424) {
    int k4 = k - 4704, m = k4 / 90, r = k4 % 90, o = r / 9, pk = r % 9;
    int s = o * 144 + 2 * m * 9 + pk;
    qw[k] = quant(w4[s]) | (quant(w4[s + 9]) << 16);
  }
}

__global__ __launch_bounds__(256, 8) void adder_main(
    const float* __restrict__ gx,
    const unsigned* __restrict__ qw,
    float* __restrict__ gout)
{
  __shared__ __align__(16) unsigned sA1[2304];
  __shared__ __align__(16) unsigned sA2[1360];

  const int t = threadIdx.x;
  const int l = t & 63;                                   // lane in wave
  const int wu = __builtin_amdgcn_readfirstlane(t >> 6);  // wave id 0..3 (SGPR)
  const int b = blockIdx.x;
  const float* img = gx + (size_t)b * 784;

  // ---------------- stage 0: A1 ghost border ----------------
  for (int k = t; k < 448; k += 256) {       // 8 planes x 56 perimeter cells
    int plane = k / 56, c = k % 56;
    int y, x;
    if (c < 15)      { y = 0;      x = c; }
    else if (c < 30) { y = 14;     x = c - 15; }
    else if (c < 43) { y = c - 29; x = 0; }
    else             { y = c - 42; x = 14; }
    sA1[plane * 288 + yoff1(y) + x] = QPAD;
  }

  // ------- stage 1: L1 [16,13,13]; wave w does op-pairs w*2, w*2+1 -------
  if (l < 52) {
    const int i = l >> 2, jq = l & 3;       // output rows i, cols j=4jq+jj
    unsigned wall[24];                      // 2 op-pairs x 12 words, uniform ->
    const unsigned* wbase = qw + wu * 24;   // one batched s_load, SGPR-resident
#pragma unroll
    for (int q = 0; q < 24; ++q) wall[q] = wbase[q];
    unsigned r[3][5], mw[3][4];
#pragma unroll
    for (int kh = 0; kh < 3; ++kh) {
      const float* rp = img + (2 * i + kh) * 28 + 8 * jq;
      float4 A = *(const float4*)(rp);
      float4 B = *(const float4*)(rp + 4);
      float2 C = *(const float2*)(rp + 8);
      r[kh][0] = quantx(A.x) | (quantx(A.y) << 16);
      r[kh][1] = quantx(A.z) | (quantx(A.w) << 16);
      r[kh][2] = quantx(B.x) | (quantx(B.y) << 16);
      r[kh][3] = quantx(B.z) | (quantx(B.w) << 16);
      r[kh][4] = quantx(C.x) | (quantx(C.y) << 16);
#pragma unroll
      for (int c = 0; c < 4; ++c) mw[kh][c] = r[kh][c + 1] & 0xFFFFu;
    }
    const int dbase = yoff1(i + 1) + 4 * jq + 1;
#pragma unroll
    for (int opp = 0; opp < 2; ++opp) {     // fully unrolled, static wall idx
      const int op = wu * 2 + opp;
      unsigned a0[4], a1[4];
#pragma unroll
      for (int jj = 0; jj < 4; ++jj) { a0[jj] = 0u; a1[jj] = 0u; }
#pragma unroll
      for (int kh = 0; kh < 3; ++kh) {
        unsigned wa01 = wall[opp * 12 + kh * 2], wa2 = wall[opp * 12 + kh * 2 + 1];
        unsigned wb01 = wall[opp * 12 + 6 + kh * 2], wb2 = wall[opp * 12 + 6 + kh * 2 + 1];
#pragma unroll
        for (int jj = 0; jj < 4; ++jj) {
          a0[jj] = sadu16(r[kh][jj], wa01, a0[jj]);
          a0[jj] = sadu16(mw[kh][jj], wa2, a0[jj]);
          a1[jj] = sadu16(r[kh][jj], wb01, a1[jj]);
          a1[jj] = sadu16(mw[kh][jj], wb2, a1[jj]);
        }
      }
      unsigned* dst = sA1 + op * 288 + dbase;
#pragma unroll
      for (int jj = 0; jj < 4; ++jj) {
        if (4 * jq + jj < 13) {
          int q0 = imax(10752 - (int)((a0[jj] + 2u) >> 2), 8192);
          int q1 = imax(10752 - (int)((a1[jj] + 2u) >> 2), 8192);
          dst[jj] = (unsigned)q0 | ((unsigned)q1 << 16);
        }
      }
    }
  }
  __syncthreads();

  // A2 ghost border: off stage-1 critical path; only read after barrier 2
  for (int k = t; k < 512; k += 256) {       // 16 planes x 32 perimeter cells
    int plane = k >> 5, c = k & 31;
    int y, x;
    if (c < 9)       { y = 0; x = c; }
    else if (c < 18) { y = 8; x = c - 9; }
    else if (c < 25) { y = c - 17; x = 0; }
    else             { y = c - 24; x = 8; }
    sA2[plane * 85 + yoff2(y) + x] = QPAD;
  }

  // ------- stage 2: L2 [32,7,7]; wave w does o = w*8..w*8+7 -------
  if (l < 49) {
    const int i = l / 7, j = l % 7;
    unsigned acc[8];
#pragma unroll
    for (int o = 0; o < 8; ++o) acc[o] = 0u;
    const unsigned* qw2 = qw + 96 + wu * 72;   // o-offset wu*8*9, uniform
#pragma unroll 1
    for (int m = 0; m < 8; ++m) {
      const unsigned* pb = sA1 + m * 288 + 39 * i + 2 * j;
      unsigned p00 = pb[0],  p01 = pb[1],  p02 = pb[2];    // yoff1(2i)   = 39i
      unsigned p10 = pb[19], p11 = pb[20], p12 = pb[21];   // yoff1(2i+1) = +19
      unsigned p20 = pb[39], p21 = pb[40], p22 = pb[41];   // yoff1(2i+2) = +39
      const unsigned* wm = qw2 + m * 288;      // uniform -> s_load
#pragma unroll
      for (int o = 0; o < 8; ++o) {
        const unsigned* w9 = wm + o * 9;
        unsigned a = acc[o];
        a = sadu16(p00, w9[0], a); a = sadu16(p01, w9[1], a); a = sadu16(p02, w9[2], a);
        a = sadu16(p10, w9[3], a); a = sadu16(p11, w9[4], a); a = sadu16(p12, w9[5], a);
        a = sadu16(p20, w9[6], a); a = sadu16(p21, w9[7], a); a = sadu16(p22, w9[8], a);
        acc[o] = a;
      }
    }
#pragma unroll
    for (int m2 = 0; m2 < 4; ++m2) {        // global ch-pair = wu*4 + m2
      int q0 = imax(24832 - (int)((acc[2 * m2] + 4u) >> 3), 8192);
      int q1 = imax(24832 - (int)((acc[2 * m2 + 1] + 4u) >> 3), 8192);
      sA2[(wu * 4 + m2) * 85 + yoff2(i + 1) + (j + 1)] = (unsigned)q0 | ((unsigned)q1 << 16);
    }
  }
  __syncthreads();

  // ------- stage 3: L3 [16,4,4]; all 64 lanes = pos16 x opair2 x m2half2.
  //         pr = wu*2 + opair; halves reduced via one shfl_xor(32) -------
  {
    const int pos = l & 15, oq = l >> 4;     // oq 0..3
    const int half = oq >> 1, opair = oq & 1;
    const int i = pos >> 2, j = pos & 3;
    const int pr = wu * 2 + opair;           // global output pair 0..7
    const unsigned* qw3 = qw + 2400 + pr * 18;
    unsigned acc0 = 0u, acc1 = 0u;
#pragma unroll 1
    for (int mm = 0; mm < 8; ++mm) {
      const int m2 = half * 8 + mm;
      const unsigned* pb = sA2 + m2 * 85 + 19 * i + 2 * j;
      unsigned p00 = pb[0],  p01 = pb[1],  p02 = pb[2];    // yoff2(2i)   = 19i
      unsigned p10 = pb[9],  p11 = pb[10], p12 = pb[11];   // yoff2(2i+1) = +9
      unsigned p20 = pb[19], p21 = pb[20], p22 = pb[21];   // yoff2(2i+2) = +19
      const unsigned* w18 = qw3 + m2 * 144;  // per-lane -> vector loads, L1-hot
      acc0 = sadu16(p00, w18[0], acc0); acc0 = sadu16(p01, w18[1], acc0);
      acc0 = sadu16(p02, w18[2], acc0); acc0 = sadu16(p10, w18[3], acc0);
      acc0 = sadu16(p11, w18[4], acc0); acc0 = sadu16(p12, w18[5], acc0);
      acc0 = sadu16(p20, w18[6], acc0); acc0 = sadu16(p21, w18[7], acc0);
      acc0 = sadu16(p22, w18[8], acc0);
      acc1 = sadu16(p00, w18[9], acc1);  acc1 = sadu16(p01, w18[10], acc1);
      acc1 = sadu16(p02, w18[11], acc1); acc1 = sadu16(p10, w18[12], acc1);
      acc1 = sadu16(p11, w18[13], acc1); acc1 = sadu16(p12, w18[14], acc1);
      acc1 = sadu16(p20, w18[15], acc1); acc1 = sadu16(p21, w18[16], acc1);
      acc1 = sadu16(p22, w18[17], acc1);
    }
    acc0 += (unsigned)__shfl_xor((int)acc0, 32);
    acc1 += (unsigned)__shfl_xor((int)acc1, 32);
    if (oq < 2) {                            // halves merged; low 32 lanes write
      int q0 = imax(26112 - (int)((acc0 + 8u) >> 4), 8192);
      int q1 = imax(26112 - (int)((acc1 + 8u) >> 4), 8192);
      // A3 pair words [pr8][pos16] @ sA1[0..], stride 17 (A1 planes dead)
      sA1[pr * 17 + pos] = (unsigned)q0 | ((unsigned)q1 << 16);
    }
  }
  __syncthreads();

  // ------- stage 4 + log_softmax: wave 0 only, shfl butterflies; waves 1-3
  //         retire here -------
  if (wu == 0) {
    unsigned acc = 0u;
    const int o = t % 10, mq = t / 10;       // meaningful for t<40
    if (t < 40) {
      const unsigned* qw4 = qw + 4704;
#pragma unroll
      for (int mm = 0; mm < 2; ++mm) {
        const int m = mq * 2 + mm;
        const unsigned* a3 = sA1 + m * 17;
        const unsigned* w9 = qw4 + (m * 10 + o) * 9;  // per-lane -> vector
#pragma unroll
        for (int kh = 0; kh < 3; ++kh)
#pragma unroll
          for (int kw = 0; kw < 3; ++kw)
            acc = sadu16(a3[kh * 4 + kw], w9[kh * 3 + kw], acc);
      }
    }
    // reduce mq groups: lane t<10 needs acc from t, t+10, t+20, t+30
    unsigned s = acc + (unsigned)__shfl((int)acc, t + 10)
                     + (unsigned)__shfl((int)acc, t + 20)
                     + (unsigned)__shfl((int)acc, t + 30);
    float lg = (t < 10) ? -(float)s * (1.0f / 1024.0f) : -1e30f;
    float mx = lg;
#pragma unroll
    for (int d = 8; d >= 1; d >>= 1) mx = fmaxf(mx, __shfl_xor(mx, d));
    float e = (t < 10) ? __expf(lg - mx) : 0.0f;
    float sum = e;
#pragma unroll
    for (int d = 8; d >= 1; d >>= 1) sum += __shfl_xor(sum, d);
    if (t < 10)
      gout[(size_t)b * 10 + t] = lg - mx - __logf(sum);
  }
}

extern "C" void kernel_launch(void* const* d_in, const int* in_sizes, int n_in,
                              void* d_out, int out_size, void* d_ws, size_t ws_size,
                              hipStream_t stream) {
  const float* x  = (const float*)d_in[0];
  const float* w1 = (const float*)d_in[1];
  const float* w2 = (const float*)d_in[2];
  const float* w3 = (const float*)d_in[3];
  const float* w4 = (const float*)d_in[4];
  unsigned* qw = (unsigned*)d_ws;           // 5424 words = 21.7 KB
  float* out = (float*)d_out;
  adder_prep<<<22, 256, 0, stream>>>(w1, w2, w3, w4, qw);
  adder_main<<<4096, 256, 0, stream>>>(x, qw, out);
}